// Round 8
// baseline (1168.847 us; speedup 1.0000x reference)
//
#include <hip/hip_runtime.h>

#define B_ 32
#define T_ 16
#define A_ 32
#define D_ 1536
#define E_ 32
#define TWO_D 3072
#define BK 64

typedef float f32x4 __attribute__((ext_vector_type(4)));
typedef float f32x2 __attribute__((ext_vector_type(2)));

// ---------------------------------------------------------------------------
// K0: group batches by expert, up to 4 per group (device-side; cat_ids is
// device mem). meta[0]=ng; group g at meta[1+6g]: {e, nb, b0, b1, b2, b3}
// (unused slots padded with b0, never read). E[ng] ~= 20.4 — reaches the
// unique-expert-slice traffic floor (~578 MB) vs pairing's ~645 MB.
// ---------------------------------------------------------------------------
__global__ void build_groups(const int* __restrict__ cat_ids,
                             int* __restrict__ meta) {
    __shared__ int cid[B_];
    __shared__ int lst[E_][B_];
    __shared__ int cnt[E_];
    const int t = threadIdx.x;
    if (t < B_) cid[t] = cat_ids[t];
    __syncthreads();
    if (t < E_) {
        int c = 0;
        for (int b = 0; b < B_; ++b)
            if (cid[b] == t) lst[t][c++] = b;
        cnt[t] = c;
    }
    __syncthreads();
    if (t == 0) {
        int ng = 0;
        for (int e = 0; e < E_; ++e) {
            const int c = cnt[e];
            for (int i = 0; i < c; i += 4) {
                const int nb = (c - i < 4) ? (c - i) : 4;
                int* m = meta + 1 + 6 * ng;
                m[0] = e;
                m[1] = nb;
                m[2] = lst[e][i];
                m[3] = (i + 1 < c) ? lst[e][i + 1] : lst[e][i];
                m[4] = (i + 2 < c) ? lst[e][i + 2] : lst[e][i];
                m[5] = (i + 3 < c) ? lst[e][i + 3] : lst[e][i];
                ++ng;
            }
        }
        meta[0] = ng;
    }
}

// ---------------------------------------------------------------------------
// K1: x = [ actions @ W1[cat] + b1[cat] | sinusoidal_pe(t) ]   (B, 16, 3072)
// grid (12, 32), block 128.
// ---------------------------------------------------------------------------
__global__ void __launch_bounds__(128)
build_x_kernel(const float* __restrict__ actions,
               const int* __restrict__ timesteps,
               const int* __restrict__ cat_ids,
               const float* __restrict__ W1,
               const float* __restrict__ b1,
               float* __restrict__ xbuf) {
    const int b   = blockIdx.y;
    const int col = blockIdx.x * 128 + threadIdx.x;
    const int e   = cat_ids[b];
    const float t = (float)timesteps[b];

    __shared__ float act[T_][A_];
    for (int i = threadIdx.x; i < T_ * A_; i += 128)
        act[i >> 5][i & 31] = actions[b * (T_ * A_) + i];
    __syncthreads();

    float acc[T_];
#pragma unroll
    for (int m = 0; m < T_; ++m) acc[m] = 0.f;

    const float* w = W1 + ((size_t)e * A_) * D_ + col;
#pragma unroll 4
    for (int k = 0; k < A_; ++k) {
        float wv = w[(size_t)k * D_];
#pragma unroll
        for (int m = 0; m < T_; ++m) acc[m] = fmaf(act[m][k], wv, acc[m]);
    }
    const float bias = b1[e * D_ + col];

    // PE over dim D=1536: concat(sin(768), cos(768)); identical for all T rows
    const int f = (col < 768) ? col : col - 768;
    const float ang = t * expf((float)f * (-9.210340371976184f / 768.0f));
    const float tau = (col < 768) ? sinf(ang) : cosf(ang);

    float* xb = xbuf + (size_t)b * T_ * TWO_D + col;
#pragma unroll
    for (int m = 0; m < T_; ++m) {
        xb[m * TWO_D]      = acc[m] + bias;
        xb[m * TWO_D + D_] = tau;
    }
}

// ---------------------------------------------------------------------------
// Grouped skinny GEMM with K-split. One block = one WAVE owning a col tile of
// one (group, k-split). COLS per thread is 4 for NB<=2 (each broadcast LDS
// b128 x-read feeds 16 FMAs — issue headroom on the 87% of traffic carried by
// small groups) and 2 for NB in {3,4} (acc VGPR cap). Weights fetched once
// per group serve NB batches' FMAs (906 -> ~578 MB weight traffic), and are
// loaded NONTEMPORAL (single-use stream; keep L2 for x/partials). x staging
// loads are REGULAR: each x k-range is re-read by all 12 col-tile blocks, so
// retention in L2/L3 matters (round-7 had nt here — audit reverted it).
// COLS=4 blocks with blockIdx.x >= 6 exit uniformly before any barrier.
// ---------------------------------------------------------------------------
template <int NB, int COLS>
__device__ __forceinline__ void gemm_body(
    const float* __restrict__ X, int K,
    int b0, int b1, int b2, int b3,
    const float* __restrict__ We,   // W + e*K*D_
    int k0, int kchunk,
    float (*xl)[T_][BK],
    float* __restrict__ pbase) {    // part + s*B*T*D
    const int c0 = blockIdx.x * (64 * COLS) + threadIdx.x * COLS;
    if (c0 >= D_) return;           // uniform per block (bx>=6 when COLS=4)
    const float* w = We + c0;

    const float* xp0 = X + (size_t)b0 * T_ * K;
    const float* xp1 = (NB > 1) ? X + (size_t)b1 * T_ * K : xp0;
    const float* xp2 = (NB > 2) ? X + (size_t)b2 * T_ * K : xp0;
    const float* xp3 = (NB > 3) ? X + (size_t)b3 * T_ * K : xp0;

    float acc[NB][T_][COLS];
#pragma unroll
    for (int bb = 0; bb < NB; ++bb)
#pragma unroll
        for (int m = 0; m < T_; ++m)
#pragma unroll
            for (int c = 0; c < COLS; ++c) acc[bb][m][c] = 0.f;

    const int tid = threadIdx.x;
    for (int kb = k0; kb < k0 + kchunk; kb += BK) {
        __syncthreads();
        // stage NB x 16 x BK x-tile (float4, coalesced along k; regular loads)
        for (int i = tid; i < NB * T_ * (BK / 4); i += 64) {
            const int bb = i / (T_ * (BK / 4));
            const int r  = i % (T_ * (BK / 4));
            const int m  = r / (BK / 4);
            const int k4 = r % (BK / 4);
            const float* xr = xp0;             // cascade, no runtime array idx
            if (NB > 1 && bb == 1) xr = xp1;
            if (NB > 2 && bb == 2) xr = xp2;
            if (NB > 3 && bb == 3) xr = xp3;
            float4 v = *reinterpret_cast<const float4*>(xr + (size_t)m * K + kb + k4 * 4);
            *reinterpret_cast<float4*>(&xl[bb][m][k4 * 4]) = v;
        }
        __syncthreads();

        const float* wkb = w + (size_t)kb * D_;
#pragma unroll 2
        for (int kk = 0; kk < BK; kk += 4) {
            const float* wp = wkb + (size_t)kk * D_;
            float wc[4][COLS];
#pragma unroll
            for (int j = 0; j < 4; ++j) {
                if constexpr (COLS == 4) {
                    f32x4 v = __builtin_nontemporal_load(
                        reinterpret_cast<const f32x4*>(wp + (size_t)j * D_));
                    wc[j][0] = v[0]; wc[j][1] = v[1]; wc[j][2] = v[2]; wc[j][3] = v[3];
                } else {
                    f32x2 v = __builtin_nontemporal_load(
                        reinterpret_cast<const f32x2*>(wp + (size_t)j * D_));
                    wc[j][0] = v[0]; wc[j][1] = v[1];
                }
            }
#pragma unroll
            for (int bb = 0; bb < NB; ++bb)
#pragma unroll
                for (int m = 0; m < T_; ++m) {
                    float4 xv = *reinterpret_cast<const float4*>(&xl[bb][m][kk]);
                    const float xa[4] = {xv.x, xv.y, xv.z, xv.w};
#pragma unroll
                    for (int j = 0; j < 4; ++j)
#pragma unroll
                        for (int c = 0; c < COLS; ++c)
                            acc[bb][m][c] = fmaf(xa[j], wc[j][c], acc[bb][m][c]);
                }
        }
    }

    const int bids[4] = {b0, b1, b2, b3};      // compile-time bb index only
#pragma unroll
    for (int bb = 0; bb < NB; ++bb) {
        float* p = pbase + (size_t)bids[bb] * T_ * D_ + c0;
#pragma unroll
        for (int m = 0; m < T_; ++m) {
            if constexpr (COLS == 4) {
                *reinterpret_cast<float4*>(p + (size_t)m * D_) =
                    make_float4(acc[bb][m][0], acc[bb][m][1],
                                acc[bb][m][2], acc[bb][m][3]);
            } else {
                *reinterpret_cast<float2*>(p + (size_t)m * D_) =
                    make_float2(acc[bb][m][0], acc[bb][m][1]);
            }
        }
    }
}

__global__ void __launch_bounds__(64)
gemm_grouped(const float* __restrict__ X, int K,
             const float* __restrict__ W,
             const int* __restrict__ meta,
             float* __restrict__ part, int kchunk) {
    const int g  = blockIdx.y;
    const int ng = meta[0];
    if (g >= ng) return;
    const int* mg = meta + 1 + 6 * g;
    const int e  = mg[0];
    const int nb = mg[1];
    const int b0 = mg[2], b1 = mg[3], b2 = mg[4], b3 = mg[5];
    const int k0 = blockIdx.z * kchunk;

    __shared__ float xl[4][T_][BK];                      // 16 KB
    const float* We = W + (size_t)e * K * D_;
    float* pbase = part + (size_t)blockIdx.z * B_ * T_ * D_;

    switch (nb) {
        case 1:  gemm_body<1, 4>(X, K, b0, b1, b2, b3, We, k0, kchunk, xl, pbase); break;
        case 2:  gemm_body<2, 4>(X, K, b0, b1, b2, b3, We, k0, kchunk, xl, pbase); break;
        case 3:  gemm_body<3, 2>(X, K, b0, b1, b2, b3, We, k0, kchunk, xl, pbase); break;
        default: gemm_body<4, 2>(X, K, b0, b1, b2, b3, We, k0, kchunk, xl, pbase); break;
    }
}

// ---------------------------------------------------------------------------
// Reduce S partials + bias (+ optional swish). float4/thread, grid 768x256.
// Partials are L2/L3-resident (<= 25 MB), so this costs ~2-4 us, not HBM time.
// ---------------------------------------------------------------------------
template <bool SWISH>
__global__ void reduce_kernel(const float* __restrict__ part, int S,
                              const float* __restrict__ bias,
                              const int* __restrict__ cat_ids,
                              float* __restrict__ out) {
    const int idx = (blockIdx.x * 256 + threadIdx.x) * 4;
    const size_t P = (size_t)B_ * T_ * D_;  // 786432
    const int b = idx / (T_ * D_);
    const int n = idx % D_;
    const int e = cat_ids[b];

    float r[4] = {0.f, 0.f, 0.f, 0.f};
    for (int s = 0; s < S; ++s) {
        float4 v = *reinterpret_cast<const float4*>(part + (size_t)s * P + idx);
        r[0] += v.x; r[1] += v.y; r[2] += v.z; r[3] += v.w;
    }
    float4 bb = *reinterpret_cast<const float4*>(bias + e * D_ + n);
    r[0] += bb.x; r[1] += bb.y; r[2] += bb.z; r[3] += bb.w;

    float4 o;
    float* op = &o.x;
#pragma unroll
    for (int j = 0; j < 4; ++j) {
        float v = r[j];
        op[j] = SWISH ? v / (1.f + expf(-v)) : v;
    }
    *reinterpret_cast<float4*>(out + idx) = o;
}

// ---------------------------------------------------------------------------
extern "C" void kernel_launch(void* const* d_in, const int* in_sizes, int n_in,
                              void* d_out, int out_size, void* d_ws, size_t ws_size,
                              hipStream_t stream) {
    const float* actions   = (const float*)d_in[0];
    const int*   timesteps = (const int*)d_in[1];
    const int*   cat_ids   = (const int*)d_in[2];
    const float* W1        = (const float*)d_in[3];
    const float* b1        = (const float*)d_in[4];
    const float* W2        = (const float*)d_in[5];
    const float* b2        = (const float*)d_in[6];
    const float* W3        = (const float*)d_in[7];
    const float* b3        = (const float*)d_in[8];
    float* out = (float*)d_out;
    float* ws  = (float*)d_ws;

    const size_t P = (size_t)B_ * T_ * D_;  // 786432 elements
    // pick k-splits to fit ws (kchunk must stay a multiple of BK=64)
    int s2 = 8, s3 = 8;
    auto need = [P](int a, int b) {
        return (size_t)(256 + (size_t)B_ * T_ * TWO_D + P + (size_t)(a + b) * P) * 4;
    };
    if (need(s2, s3) > ws_size) { s2 = 6; s3 = 4; }
    if (need(s2, s3) > ws_size) { s2 = 4; s3 = 4; }
    if (need(s2, s3) > ws_size) { s2 = 2; s3 = 2; }
    if (need(s2, s3) > ws_size) { s2 = 1; s3 = 1; }

    int*   meta  = (int*)ws;                 // 193 ints used
    float* xbuf  = ws + 256;                 // B*16*3072
    float* hpart = xbuf + (size_t)B_ * T_ * TWO_D;
    float* hbuf  = hpart + (size_t)s2 * P;
    float* opart = hbuf + P;

    build_groups<<<1, 64, 0, stream>>>(cat_ids, meta);
    build_x_kernel<<<dim3(12, 32), 128, 0, stream>>>(actions, timesteps, cat_ids,
                                                     W1, b1, xbuf);
    // h = swish(x @ W2[e] + b2[e]),  K = 3072
    gemm_grouped<<<dim3(12, 32, s2), 64, 0, stream>>>(xbuf, TWO_D, W2, meta,
                                                      hpart, TWO_D / s2);
    reduce_kernel<true><<<768, 256, 0, stream>>>(hpart, s2, b2, cat_ids, hbuf);
    // out = h @ W3[e] + b3[e],       K = 1536
    gemm_grouped<<<dim3(12, 32, s3), 64, 0, stream>>>(hbuf, D_, W3, meta,
                                                      opart, D_ / s3);
    reduce_kernel<false><<<768, 256, 0, stream>>>(opart, s3, b3, cat_ids, out);
}